// Round 12
// baseline (242.550 us; speedup 1.0000x reference)
//
#include <hip/hip_runtime.h>
#include <hip/hip_bf16.h>

typedef __attribute__((ext_vector_type(4))) float f32x4;
typedef __attribute__((ext_vector_type(4))) short s16x4;
typedef __attribute__((ext_vector_type(8))) short s16x8;
typedef __attribute__((ext_vector_type(8))) __bf16 bf16x8;

#define DEV static __device__ __forceinline__

DEV float bf2f(ushort u){
  unsigned x = ((unsigned)u) << 16;
  return __builtin_bit_cast(float, x);
}
DEV ushort f2bf(float f){
  unsigned x = __builtin_bit_cast(unsigned, f);
  x += 0x7fffu + ((x >> 16) & 1u);
  return (ushort)(x >> 16);
}
DEV void load_lds16(const void* g, void* l){
  __builtin_amdgcn_global_load_lds((const __attribute__((address_space(1))) void*)g,
                                   (__attribute__((address_space(3))) void*)l, 16, 0, 0);
}

// ------- stage 0 (merged): x fp32->bf16  +  W [K][N] fp32 -> Wt [N][K] bf16
__global__ __launch_bounds__(256) void k_prep(
    const float* __restrict__ x, ushort* __restrict__ xb,
    const float* __restrict__ Wq, const float* __restrict__ Wk,
    const float* __restrict__ Wv, const float* __restrict__ Wp,
    ushort* __restrict__ qkvT, ushort* __restrict__ wpT)
{
  __shared__ float tile[32][33];
  int bid = blockIdx.x, tid = threadIdx.x;
  if (bid < 8192) {
    int i = bid * 256 + tid;
    const f32x4* p = (const f32x4*)(x + (size_t)i * 8);
    f32x4 a = p[0], b = p[1];
    s16x8 o;
    o[0]=(short)f2bf(a[0]); o[1]=(short)f2bf(a[1]); o[2]=(short)f2bf(a[2]); o[3]=(short)f2bf(a[3]);
    o[4]=(short)f2bf(b[0]); o[5]=(short)f2bf(b[1]); o[6]=(short)f2bf(b[2]); o[7]=(short)f2bf(b[3]);
    *(s16x8*)(xb + (size_t)i * 8) = o;
  } else {
    int r = bid - 8192;                     // 0..4095
    int z = r >> 10; r &= 1023;
    const float* W = (z == 0) ? Wq : (z == 1) ? Wk : (z == 2) ? Wv : Wp;
    ushort* out = (z < 3) ? (qkvT + (size_t)z * 1024 * 1024) : wpT;
    int bx = (r & 31) * 32, by = (r >> 5) * 32;
    int tx = tid & 31, ty = tid >> 5;
    #pragma unroll
    for (int j = 0; j < 32; j += 8)
      tile[ty + j][tx] = W[(size_t)(by + ty + j) * 1024 + bx + tx];
    __syncthreads();
    #pragma unroll
    for (int j = 0; j < 32; j += 8)
      out[(size_t)(bx + ty + j) * 1024 + by + tx] = f2bf(tile[tx][ty + j]);
  }
}

// ---- MFMA GEMM, 256x256, BK=64, 8-phase (mh x nh quadrants, reg-held frags)
// C[M][N] = A[M][K]*Bt[N][K]^T, K=1024. 512 thr = 8 waves (2Mx4N), wave tile
// 128x64. Per K-tile 4 phases: (mh0,nh0),(mh0,nh1),(mh1,nh1),(mh1,nh0), each
// 16 MFMA (4m x 2n x 2kk). A-frags read once per mh (8 ds_read), B-frags once
// per nh (4 ds_read); nh0 HELD IN REGS through p4 -> p4/p8 have 0 reads.
// ds_read/tile = 24 (R7-equal; R10's 32 doubled conflicts).
// Region last-reads (tile in buf0): A-r0r2@p1, B@p2, A-r1r3@p3 -> stages:
//   p1: B(2i+1)->buf1[4]   p2: A02(2i+2)->buf0[2]  p3: B(2i+2)->buf0[4]
//   p4: A13(2i+2)->buf0[2] p6: A02(2i+3)->buf1[2]  p8: A13(2i+3)->buf1[2]
// EVERY stage is issued in a phase strictly after its region's last read,
// with barrier+lgkmcnt(0) between (R8 race invariant; dual-barrier makes it
// wave-safe). Counted waits: vmcnt(8)@p4-end, vmcnt(4)@p8-end (FIFO-sim'd
// incl. prologue {t0 full + t1-A02/A13, vmcnt(4)} and peeled i=7 {vmcnt(0)
// @p4}). Leads: A 4-7 phases (HBM-safe), B 3-6 (L2 weights).
// Phase: {reads; stage; BAR; lgkm0; sched_bar; setprio1; 16 MFMA; setprio0;
// [vmcnt]; BAR}.
template<int MODE>
__global__ __launch_bounds__(512, 1) void k_gemm(
    const ushort* __restrict__ A, const ushort* __restrict__ Bt,
    const float* __restrict__ b0, const float* __restrict__ b1, const float* __restrict__ b2,
    ushort* __restrict__ oQ, ushort* __restrict__ oK, ushort* __restrict__ oV,
    float* __restrict__ oF, int N)
{
  const int K = 1024;
  __shared__ ushort ldsA[2][16384];         // slab0/slab1, 32KB each
  __shared__ ushort ldsB[2][16384];

  int wg = blockIdx.x;
  int cpx = gridDim.x >> 3;                 // grids are multiples of 8
  wg = (wg & 7) * cpx + (wg >> 3);          // XCD-aware swizzle (bijective)
  int nbn = N >> 8;
  int bmi = wg / nbn, bni = wg - bmi * nbn;
  int m0 = bmi << 8, n0 = bni << 8;
  int tid = threadIdx.x, wid = tid >> 6, lane = tid & 63;
  int wr = wid >> 2, wc = wid & 3;
  int hi = lane >> 4, L = lane & 15;

  // staging sources (linear LDS dest, inverse-swizzled global source)
  int rr = tid >> 3;                                   // row within 8KB round
  int gaA = ((tid & 7) ^ (rr & 7)) << 3;               // A src col (elements)
  int gaB = ((tid & 7) ^ ((tid >> 5) & 7)) << 3;       // B src col (elements)
  const ushort* gA = A  + (size_t)(m0 + rr) * K + gaA;
  const ushort* gB = Bt + (size_t)(n0 + rr) * K + gaB;
  int ldst = wid << 10;                                // per-wave 1KB sliver

  // fragment read addresses
  int swz = (hi ^ (L & 7)) << 4;            // ^ 64 bytes for kk=1
  int arow = (wr * 128 + L) << 7;           // + mh*8192 + m*2048
  int brow = ((wc * 64 + L * 4)) << 7;      // + n*128

  f32x4 acc[8][4] = {};
  bf16x8 af[4][2];                          // [m][kk], refreshed per mh
  bf16x8 bf[4][2];                          // [n][kk], n-half refreshed per nh

  #define RD_A(BASE, MH)                                                       \
    _Pragma("unroll")                                                          \
    for (int m = 0; m < 4; ++m)                                                \
      _Pragma("unroll")                                                        \
      for (int kk = 0; kk < 2; ++kk)                                           \
        af[m][kk] = *(const bf16x8*)((BASE) + arow + (MH) * 8192 + (m << 11) + (swz ^ (kk << 6)));
  #define RD_B(BASE, NH)                                                       \
    _Pragma("unroll")                                                          \
    for (int j = 0; j < 2; ++j)                                                \
      _Pragma("unroll")                                                        \
      for (int kk = 0; kk < 2; ++kk)                                           \
        bf[(NH) * 2 + j][kk] = *(const bf16x8*)((BASE) + brow + (((NH) * 2 + j) << 7) + (swz ^ (kk << 6)));
  #define MFMAQ(MH, NH)                                                        \
    _Pragma("unroll")                                                          \
    for (int m = 0; m < 4; ++m)                                                \
      _Pragma("unroll")                                                        \
      for (int j = 0; j < 2; ++j)                                              \
        _Pragma("unroll")                                                      \
        for (int kk = 0; kk < 2; ++kk)                                         \
          acc[(MH) * 4 + m][(NH) * 2 + j] =                                    \
            __builtin_amdgcn_mfma_f32_16x16x32_bf16(af[m][kk], bf[(NH) * 2 + j][kk], \
                                                    acc[(MH) * 4 + m][(NH) * 2 + j], 0, 0, 0);

  // stages: A rounds r0-r3 = 8KB each (rows 0-63,64-127,128-191,192-255)
  #define ST_A02(SA_, kof) { load_lds16(gA + (kof),                   (SA_) + ldst);          \
                             load_lds16(gA + (size_t)128 * K + (kof), (SA_) + 16384 + ldst); }
  #define ST_A13(SA_, kof) { load_lds16(gA + (size_t) 64 * K + (kof), (SA_) + 8192  + ldst);  \
                             load_lds16(gA + (size_t)192 * K + (kof), (SA_) + 24576 + ldst); }
  #define ST_B4(SB_, kof)  { load_lds16(gB + (kof),                   (SB_) + ldst);          \
                             load_lds16(gB + (size_t) 64 * K + (kof), (SB_) + 8192  + ldst);  \
                             load_lds16(gB + (size_t)128 * K + (kof), (SB_) + 16384 + ldst);  \
                             load_lds16(gB + (size_t)192 * K + (kof), (SB_) + 24576 + ldst); }

  #define PHASE(READS, STG, MFMAS, WAIT)                                       \
  { READS                                                                      \
    STG                                                                        \
    __builtin_amdgcn_s_barrier();                                              \
    asm volatile("s_waitcnt lgkmcnt(0)" ::: "memory");                         \
    __builtin_amdgcn_sched_barrier(0);                                         \
    __builtin_amdgcn_s_setprio(1);                                             \
    MFMAS                                                                      \
    __builtin_amdgcn_s_setprio(0);                                             \
    WAIT                                                                       \
    __builtin_amdgcn_s_barrier(); }

  char* SA0 = (char*)&ldsA[0][0];
  char* SA1 = (char*)&ldsA[1][0];
  char* SB0 = (char*)&ldsB[0][0];
  char* SB1 = (char*)&ldsB[1][0];
  const char* LA0 = (const char*)&ldsA[0][0];
  const char* LA1 = (const char*)&ldsA[1][0];
  const char* LB0 = (const char*)&ldsB[0][0];
  const char* LB1 = (const char*)&ldsB[1][0];

  // prologue: t0 full -> slab0 (8 loads), t1 A-rounds -> slab1 (4 loads)
  ST_A02(SA0, 0) ST_A13(SA0, 0) ST_B4(SB0, 0)
  ST_A02(SA1, 64) ST_A13(SA1, 64)
  asm volatile("s_waitcnt vmcnt(4)" ::: "memory");   // t0 landed; t1-A in flight
  __builtin_amdgcn_s_barrier();

  for (int i = 0; i < 8; ++i) {
    size_t ko  = (size_t)(2 * i + 1) << 6;
    size_t ke2 = (size_t)(2 * i + 2) << 6;
    size_t ko2 = (size_t)(2 * i + 3) << 6;
    bool se = (2 * i + 2) < 16, so = (2 * i + 3) < 16;

    // ---- tile 2i (slab0) ----
    PHASE( RD_A(LA0, 0) RD_B(LB0, 0), { ST_B4(SB1, ko) },          MFMAQ(0, 0), )
    PHASE( RD_B(LB0, 1),              { if (se) ST_A02(SA0, ke2) }, MFMAQ(0, 1), )
    PHASE( RD_A(LA0, 1),              { if (se) ST_B4(SB0, ke2) },  MFMAQ(1, 1), )
    PHASE( ,                          { if (se) ST_A13(SA0, ke2) }, MFMAQ(1, 0),
           { if (se) asm volatile("s_waitcnt vmcnt(8)" ::: "memory");
             else    asm volatile("s_waitcnt vmcnt(0)" ::: "memory"); })
    // ---- tile 2i+1 (slab1) ----
    PHASE( RD_A(LA1, 0) RD_B(LB1, 0), ,                            MFMAQ(0, 0), )
    PHASE( RD_B(LB1, 1),              { if (so) ST_A02(SA1, ko2) }, MFMAQ(0, 1), )
    PHASE( RD_A(LA1, 1),              ,                            MFMAQ(1, 1), )
    PHASE( ,                          { if (so) ST_A13(SA1, ko2) }, MFMAQ(1, 0),
           { if (so) asm volatile("s_waitcnt vmcnt(4)" ::: "memory"); })
  }
  #undef PHASE
  #undef RD_A
  #undef RD_B
  #undef MFMAQ

  // ---- epilogue: lane holds 4 contiguous cols (cb4..cb4+3) per row
  int row0 = m0 + wr * 128 + (hi << 2);
  int cb4 = n0 + wc * 64 + (L << 2);
  if constexpr (MODE == 0) {
    f32x4 bias; ushort* dst; bool act;
    if (cb4 < 1024)      { bias = *(const f32x4*)(b0 + cb4);          dst = oQ + cb4;          act = true;  }
    else if (cb4 < 2048) { bias = *(const f32x4*)(b1 + (cb4 - 1024)); dst = oK + (cb4 - 1024); act = true;  }
    else                 { bias = *(const f32x4*)(b2 + (cb4 - 2048)); dst = oV + (cb4 - 2048); act = false; }
    #pragma unroll
    for (int m = 0; m < 8; ++m)
      #pragma unroll
      for (int j = 0; j < 4; ++j) {
        int r = row0 + m * 16 + j;
        s16x4 w;
        #pragma unroll
        for (int n = 0; n < 4; ++n) {
          float v = acc[m][n][j] + bias[n];
          if (act) v = (v > 0.f) ? (v + 1.f) : __expf(v);   // elu(v)+1
          w[n] = (short)f2bf(v);
        }
        *(s16x4*)(dst + (size_t)r * 1024) = w;
      }
  } else {
    f32x4 bias = *(const f32x4*)(b0 + cb4);
    #pragma unroll
    for (int m = 0; m < 8; ++m)
      #pragma unroll
      for (int j = 0; j < 4; ++j) {
        int r = row0 + m * 16 + j;
        f32x4 w;
        #pragma unroll
        for (int n = 0; n < 4; ++n) w[n] = acc[m][n][j] + bias[n];
        *(f32x4*)(oF + (size_t)r * 1024 + cb4) = w;
      }
  }
}

// ---------------- stage 2: kv partials, NO atomics, no spill ---------------
__global__ __launch_bounds__(256, 2) void k_kv(
    const ushort* __restrict__ kbuf, const ushort* __restrict__ vbuf,
    float* __restrict__ kvp, float* __restrict__ skp)
{
  __shared__ ushort tile[2][8192];          // [buf][ K 8KB | V 8KB ]
  __shared__ float red[64 * 68];            // pad 64->68 floats per row
  __shared__ float skred[4][64];

  int bh = blockIdx.x >> 3, chunk = blockIdx.x & 7;
  int b = bh >> 4, h = bh & 15;
  int tid = threadIdx.x, wid = tid >> 6, lane = tid & 63;
  int d0 = (lane >> 3) << 3, e0 = (lane & 7) << 3;

  size_t gbase = ((size_t)b * 4096 + chunk * 512 + wid * 16 + (lane >> 3)) * 1024
               + h * 64 + (lane & 7) * 8;

  float acc[8][8] = {};
  float sk[8] = {};

  #define STAGE_KV(bp, c)                                                     \
  { char* base_ = (char*)&tile[bp][0] + (wid << 11);                          \
    size_t g_ = gbase + (size_t)(c) * 65536;                                  \
    load_lds16(kbuf + g_,        base_);                                      \
    load_lds16(kbuf + g_ + 8192, base_ + 1024);                               \
    load_lds16(vbuf + g_,        base_ + 8192);                               \
    load_lds16(vbuf + g_ + 8192, base_ + 9216); }

  STAGE_KV(0, 0)

  for (int c = 0; c < 8; ++c) {
    if (c + 1 < 8) {
      STAGE_KV((c + 1) & 1, c + 1)
      asm volatile("s_waitcnt vmcnt(4)" ::: "memory");   // tile c's 4 landed
    } else {
      asm volatile("s_waitcnt vmcnt(0)" ::: "memory");
    }
    __builtin_amdgcn_s_barrier();
    const ushort* Ks = &tile[c & 1][0];
    const ushort* Vs = &tile[c & 1][4096];
    #pragma unroll
    for (int t = 0; t < 16; ++t) {
      int nn = (wid << 4) + t;
      s16x8 k8 = *(const s16x8*)(Ks + nn * 64 + d0);
      s16x8 v8 = *(const s16x8*)(Vs + nn * 64 + e0);
      float kf[8], vf[8];
      #pragma unroll
      for (int i = 0; i < 8; ++i) { kf[i] = bf2f((ushort)k8[i]); vf[i] = bf2f((ushort)v8[i]); }
      #pragma unroll
      for (int i = 0; i < 8; ++i) {
        sk[i] += kf[i];
        #pragma unroll
        for (int j = 0; j < 8; ++j) acc[i][j] += kf[i] * vf[j];
      }
    }
    __builtin_amdgcn_sched_barrier(0);
    __builtin_amdgcn_s_barrier();
  }
  #undef STAGE_KV

  for (int w = 0; w < 4; ++w) {
    if (wid == w) {
      #pragma unroll
      for (int i = 0; i < 8; ++i)
        #pragma unroll
        for (int j4 = 0; j4 < 2; ++j4) {
          f32x4 v4;
          v4[0] = acc[i][j4 * 4 + 0]; v4[1] = acc[i][j4 * 4 + 1];
          v4[2] = acc[i][j4 * 4 + 2]; v4[3] = acc[i][j4 * 4 + 3];
          float* p = &red[(d0 + i) * 68 + e0 + j4 * 4];
          if (w == 0) *(f32x4*)p = v4;
          else        { f32x4 o = *(const f32x4*)p; *(f32x4*)p = o + v4; }
        }
    }
    __syncthreads();
  }

  size_t kvbase = ((size_t)chunk * 64 + bh) * 4096;
  #pragma unroll
  for (int i = 0; i < 16; ++i) {
    int el = tid + i * 256;
    kvp[kvbase + el] = red[(el >> 6) * 68 + (el & 63)];
  }
  if ((lane & 7) == 0) {
    #pragma unroll
    for (int i = 0; i < 8; ++i) skred[wid][d0 + i] = sk[i];
  }
  __syncthreads();
  if (tid < 64) {
    float s = 0.f;
    #pragma unroll
    for (int w = 0; w < 4; ++w) s += skred[w][tid];
    skp[(((size_t)chunk * 64 + bh) << 6) + tid] = s;
  }
}

// ---------------- stage 3 (MFMA): y = (q @ kv) / (q . sumk) ----------------
__global__ __launch_bounds__(512, 2) void k_num(
    const ushort* __restrict__ qbuf, const float* __restrict__ kvp,
    const float* __restrict__ skp, ushort* __restrict__ ybuf)
{
  __shared__ float kvf[4096];               // 16KB
  __shared__ ushort kvtb[4096];             // 8KB  [e][d] bf16, swizzled
  __shared__ ushort skb[64];

  int bh = blockIdx.x >> 3, chunk = blockIdx.x & 7;
  int b = bh >> 4, h = bh & 15;
  int tid = threadIdx.x, wid = tid >> 6, lane = tid & 63;
  int hi = lane >> 4, L = lane & 15;

  #pragma unroll
  for (int i = 0; i < 2; ++i) {
    int i4 = tid + i * 512;
    f32x4 s = {0.f, 0.f, 0.f, 0.f};
    #pragma unroll
    for (int sl = 0; sl < 8; ++sl)
      s += *(const f32x4*)&kvp[(((size_t)sl * 64 + bh) << 12) + ((size_t)i4 << 2)];
    *(f32x4*)&kvf[i4 << 2] = s;
  }
  if (tid < 64) {
    float s = 0.f;
    #pragma unroll
    for (int sl = 0; sl < 8; ++sl) s += skp[(((size_t)sl * 64 + bh) << 6) + tid];
    skb[tid] = f2bf(s);
  }
  __syncthreads();
  {
    int e = tid >> 3, dg = tid & 7;
    s16x8 o;
    #pragma unroll
    for (int j = 0; j < 8; ++j) o[j] = (short)f2bf(kvf[(dg * 8 + j) * 64 + e]);
    *(s16x8*)((char*)kvtb + e * 128 + ((dg ^ (e & 7)) << 4)) = o;
  }
  __syncthreads();

  size_t r0 = (size_t)b * 4096 + chunk * 512 + wid * 64;
  const ushort* qb = qbuf + (r0 + L) * 1024 + h * 64 + hi * 8;

  f32x4 acc[4][4] = {};
  f32x4 accd[4] = {};
  #pragma unroll
  for (int kk = 0; kk < 2; ++kk) {
    bf16x8 bfr[4], bfd;
    bfd = *(const bf16x8*)((const char*)skb + kk * 64 + hi * 16);  // broadcast
    #pragma unroll
    for (int n = 0; n < 4; ++n) {
      int e = L * 4 + n;
      bfr[n] = *(const bf16x8*)((char*)kvtb + e * 128 + ((((kk << 2) | hi) ^ (e & 7)) << 4));
    }
    #pragma unroll
    for (int m = 0; m < 4; ++m) {
      bf16x8 af = *(const bf16x8*)(qb + (size_t)m * 16 * 1024 + kk * 32);
      #pragma unroll
      for (int n = 0; n < 4; ++n)
        acc[m][n] = __builtin_amdgcn_mfma_f32_16x16x32_bf16(af, bfr[n], acc[m][n], 0, 0, 0);
      accd[m] = __builtin_amdgcn_mfma_f32_16x16x32_bf16(af, bfd, accd[m], 0, 0, 0);
    }
  }

  #pragma unroll
  for (int m = 0; m < 4; ++m)
    #pragma unroll
    for (int j = 0; j < 4; ++j) {
      float inv = 1.0f / accd[m][j];
      s16x4 w;
      #pragma unroll
      for (int n = 0; n < 4; ++n) w[n] = (short)f2bf(acc[m][n][j] * inv);
      *(s16x4*)(ybuf + (r0 + m * 16 + hi * 4 + j) * 1024 + h * 64 + L * 4) = w;
    }
}

extern "C" void kernel_launch(void* const* d_in, const int* in_sizes, int n_in,
                              void* d_out, int out_size, void* d_ws, size_t ws_size,
                              hipStream_t stream)
{
  const float* x  = (const float*)d_in[0];
  const float* Wq = (const float*)d_in[1];
  const float* bq = (const float*)d_in[2];
  const float* Wk = (const float*)d_in[3];
  const float* bk = (const float*)d_in[4];
  const float* Wv = (const float*)d_in[5];
  const float* bv = (const float*)d_in[6];
  const float* Wp = (const float*)d_in[7];
  const float* bp = (const float*)d_in[8];

  char* ws = (char*)d_ws;
  ushort* xb    = (ushort*)(ws + 0);          // 33,554,432 B  x in bf16 (dead after QKV)
  ushort* qkvT  = (ushort*)(ws + 33554432);   //  6,291,456 B  [Wq|Wk|Wv]^T bf16
  ushort* wpT   = (ushort*)(ws + 39845888);   //  2,097,152 B  Wp^T bf16
  ushort* ybuf  = (ushort*)(ws + 41943040);   // 33,554,432 B  k (then aliased as y)
  // kv partial slabs overlay the DEAD xb region (k_kv runs after QKV GEMM):
  float*  kvp   = (float*)(ws + 0);           //  8,388,608 B  kvp[8][64][4096]
  float*  skp   = (float*)(ws + 8388608);     //    131,072 B  skp[8][64][64]

  // v and q live in d_out (67,108,864 B of scratch, dead before final GEMM)
  ushort* vbuf = (ushort*)d_out;
  ushort* qbuf = (ushort*)d_out + 16777216;
  ushort* kbuf = ybuf;

  k_prep<<<12288, 256, 0, stream>>>(x, xb, Wq, Wk, Wv, Wp, qkvT, wpT);
  k_gemm<0><<<768, 512, 0, stream>>>(xb, qkvT, bq, bk, bv, qbuf, kbuf, vbuf, nullptr, 3072);
  k_kv<<<512, 256, 0, stream>>>(kbuf, vbuf, kvp, skp);
  k_num<<<512, 512, 0, stream>>>(qbuf, kvp, skp, ybuf);
  k_gemm<1><<<256, 512, 0, stream>>>(ybuf, wpT, bp, nullptr, nullptr,
                                     nullptr, nullptr, nullptr, (float*)d_out, 1024);
}

// Round 13
// 226.342 us; speedup vs baseline: 1.0716x; 1.0716x over previous
//
#include <hip/hip_runtime.h>
#include <hip/hip_bf16.h>

typedef __attribute__((ext_vector_type(4))) float f32x4;
typedef __attribute__((ext_vector_type(4))) short s16x4;
typedef __attribute__((ext_vector_type(8))) short s16x8;
typedef __attribute__((ext_vector_type(8))) __bf16 bf16x8;

#define DEV static __device__ __forceinline__

DEV float bf2f(ushort u){
  unsigned x = ((unsigned)u) << 16;
  return __builtin_bit_cast(float, x);
}
DEV ushort f2bf(float f){
  unsigned x = __builtin_bit_cast(unsigned, f);
  x += 0x7fffu + ((x >> 16) & 1u);
  return (ushort)(x >> 16);
}
DEV void load_lds16(const void* g, void* l){
  __builtin_amdgcn_global_load_lds((const __attribute__((address_space(1))) void*)g,
                                   (__attribute__((address_space(3))) void*)l, 16, 0, 0);
}

// ------- stage 0 (merged): x fp32->bf16  +  W [K][N] fp32 -> Wt [N][K] bf16
__global__ __launch_bounds__(256) void k_prep(
    const float* __restrict__ x, ushort* __restrict__ xb,
    const float* __restrict__ Wq, const float* __restrict__ Wk,
    const float* __restrict__ Wv, const float* __restrict__ Wp,
    ushort* __restrict__ qkvT, ushort* __restrict__ wpT)
{
  __shared__ float tile[32][33];
  int bid = blockIdx.x, tid = threadIdx.x;
  if (bid < 8192) {
    int i = bid * 256 + tid;
    const f32x4* p = (const f32x4*)(x + (size_t)i * 8);
    f32x4 a = p[0], b = p[1];
    s16x8 o;
    o[0]=(short)f2bf(a[0]); o[1]=(short)f2bf(a[1]); o[2]=(short)f2bf(a[2]); o[3]=(short)f2bf(a[3]);
    o[4]=(short)f2bf(b[0]); o[5]=(short)f2bf(b[1]); o[6]=(short)f2bf(b[2]); o[7]=(short)f2bf(b[3]);
    *(s16x8*)(xb + (size_t)i * 8) = o;
  } else {
    int r = bid - 8192;                     // 0..4095
    int z = r >> 10; r &= 1023;
    const float* W = (z == 0) ? Wq : (z == 1) ? Wk : (z == 2) ? Wv : Wp;
    ushort* out = (z < 3) ? (qkvT + (size_t)z * 1024 * 1024) : wpT;
    int bx = (r & 31) * 32, by = (r >> 5) * 32;
    int tx = tid & 31, ty = tid >> 5;
    #pragma unroll
    for (int j = 0; j < 32; j += 8)
      tile[ty + j][tx] = W[(size_t)(by + ty + j) * 1024 + bx + tx];
    __syncthreads();
    #pragma unroll
    for (int j = 0; j < 32; j += 8)
      out[(size_t)(bx + ty + j) * 1024 + by + tx] = f2bf(tile[tx][ty + j]);
  }
}

// ---------------- MFMA GEMM, 256x256, BK=64, 4-phase + FRAG READ-AHEAD -----
// R7 schedule — proven best of 8 GEMM variants tried this session
// (R3/R5/R7 ~115us; R2 130; R4 burst 129; R8 8-phase raced; R10 8-phase
// 146us doubled conflicts; R12 8-phase reg-held 130us barrier overhead).
// Key properties: frag double-buffer (reads for phase p+1 issued before
// MFMA of p, compiler emits counted lgkmcnt -> LDS delivery overlaps MFMA);
// stages only into regions whose reads drained in a PRIOR phase (race-free
// invariant; LDS service latency ~770cy can exceed DMA L2 latency ~200cy,
// so same-phase stage-into-read-region is a real race - R8's lesson).
template<int MODE>
__global__ __launch_bounds__(512, 1) void k_gemm(
    const ushort* __restrict__ A, const ushort* __restrict__ Bt,
    const float* __restrict__ b0, const float* __restrict__ b1, const float* __restrict__ b2,
    ushort* __restrict__ oQ, ushort* __restrict__ oK, ushort* __restrict__ oV,
    float* __restrict__ oF, int N)
{
  const int K = 1024;
  const int NT = 16;                        // K / 64
  __shared__ ushort ldsA[2][16384];         // 2 x 32KB: [256 rows][64 cols bf16]
  __shared__ ushort ldsB[2][16384];

  int wg = blockIdx.x;
  int cpx = gridDim.x >> 3;                 // grids are multiples of 8
  wg = (wg & 7) * cpx + (wg >> 3);          // XCD-aware swizzle (bijective)
  int nbn = N >> 8;
  int bmi = wg / nbn, bni = wg - bmi * nbn;
  int m0 = bmi << 8, n0 = bni << 8;
  int tid = threadIdx.x, wid = tid >> 6, lane = tid & 63;
  int wr = wid >> 2, wc = wid & 3;
  int hi = lane >> 4, L = lane & 15;

  int rr = tid >> 3;                                   // row within 8KB round
  int gaA = ((tid & 7) ^ (rr & 7)) << 3;               // A src col (elements)
  int gaB = ((tid & 7) ^ ((tid >> 5) & 7)) << 3;       // B src col (elements)
  const ushort* gA = A  + (size_t)(m0 + rr) * K + gaA;
  const ushort* gB = Bt + (size_t)(n0 + rr) * K + gaB;
  int ldst = wid << 10;                                // + round*8192

  int swz = (hi ^ (L & 7)) << 4;            // ^ 64 for kk=1
  int arow = (wr * 128 + L) << 7;           // + mh*8192 + m*2048
  int brow = ((wc * 64 + L * 4)) << 7;      // + n*128

  f32x4 acc[8][4] = {};
  bf16x8 aX[4], aY[4], bX[4], bY[4];

  #define RD_A(SET, BASE, MH, KX)                                              \
    _Pragma("unroll")                                                          \
    for (int m = 0; m < 4; ++m)                                                \
      SET[m] = *(const bf16x8*)((BASE) + arow + (MH) * 8192 + (m << 11) + (swz ^ (KX)));
  #define RD_B(SET, BASE, KX)                                                  \
    _Pragma("unroll")                                                          \
    for (int n = 0; n < 4; ++n)                                                \
      SET[n] = *(const bf16x8*)((BASE) + brow + (n << 7) + (swz ^ (KX)));
  #define MF(MOFF, ASET, BSET)                                                 \
    __builtin_amdgcn_s_setprio(1);                                             \
    _Pragma("unroll")                                                          \
    for (int m = 0; m < 4; ++m)                                                \
      _Pragma("unroll")                                                        \
      for (int n = 0; n < 4; ++n)                                              \
        acc[m + (MOFF)][n] =                                                   \
          __builtin_amdgcn_mfma_f32_16x16x32_bf16(ASET[m], BSET[n], acc[m + (MOFF)][n], 0, 0, 0); \
    __builtin_amdgcn_s_setprio(0);

  #define ST_B0(SB, kof) load_lds16(gB + (kof),                   (SB) + ldst);
  #define ST_B1(SB, kof) load_lds16(gB + (size_t) 64 * K + (kof), (SB) + 8192  + ldst);
  #define ST_B2(SB, kof) load_lds16(gB + (size_t)128 * K + (kof), (SB) + 16384 + ldst);
  #define ST_B3(SB, kof) load_lds16(gB + (size_t)192 * K + (kof), (SB) + 24576 + ldst);
  #define ST_A0(SA, kof) load_lds16(gA + (kof),                   (SA) + ldst);
  #define ST_A2(SA, kof) load_lds16(gA + (size_t)128 * K + (kof), (SA) + 16384 + ldst);
  #define ST_A1(SA, kof) load_lds16(gA + (size_t) 64 * K + (kof), (SA) + 8192  + ldst);
  #define ST_A3(SA, kof) load_lds16(gA + (size_t)192 * K + (kof), (SA) + 24576 + ldst);

  {
    char* SA0 = (char*)&ldsA[0][0];
    char* SB0 = (char*)&ldsB[0][0];
    char* SB1 = (char*)&ldsB[1][0];
    ST_B0(SB0, 0) ST_B1(SB0, 0) ST_B2(SB0, 0) ST_B3(SB0, 0)
    ST_A0(SA0, 0) ST_A2(SA0, 0) ST_A1(SA0, 0) ST_A3(SA0, 0)
    ST_B0(SB1, 64) ST_B1(SB1, 64)
  }
  asm volatile("s_waitcnt vmcnt(4)" ::: "memory");
  __builtin_amdgcn_s_barrier();
  RD_A(aX, (const char*)&ldsA[0][0], 0, 0)
  RD_B(bX, (const char*)&ldsB[0][0], 0)

  int buf = 0;
  for (int t = 0; t < NT; ++t) {
    const char* LA = (const char*)&ldsA[buf][0];
    const char* LB = (const char*)&ldsB[buf][0];
    char* SAn = (char*)&ldsA[buf ^ 1][0];
    char* SBn = (char*)&ldsB[buf ^ 1][0];
    char* SBc = (char*)&ldsB[buf][0];
    size_t k1 = (size_t)(t + 1) << 6;
    size_t k2 = (size_t)(t + 2) << 6;
    bool st1 = (t + 1) < NT, st2 = (t + 2) < NT;

    if (st1) asm volatile("s_waitcnt vmcnt(2)" ::: "memory");
    else     asm volatile("s_waitcnt vmcnt(0)" ::: "memory");
    __builtin_amdgcn_s_barrier();
    RD_A(aY, LA, 1, 0)
    if (st1) { ST_B2(SBn, k1) ST_B3(SBn, k1) }
    __builtin_amdgcn_sched_barrier(0);
    MF(0, aX, bX)

    __builtin_amdgcn_s_barrier();
    RD_A(aX, LA, 1, 64)
    RD_B(bY, LB, 64)
    if (st1) { ST_A0(SAn, k1) ST_A2(SAn, k1) }
    __builtin_amdgcn_sched_barrier(0);
    MF(4, aY, bX)

    __builtin_amdgcn_s_barrier();
    RD_A(aY, LA, 0, 64)
    if (st1) { ST_A1(SAn, k1) ST_A3(SAn, k1) }
    __builtin_amdgcn_sched_barrier(0);
    MF(4, aX, bY)

    asm volatile("s_waitcnt vmcnt(2)" ::: "memory");
    __builtin_amdgcn_s_barrier();
    if (st1) { RD_A(aX, SAn, 0, 0) RD_B(bX, SBn, 0) }
    if (st2) { ST_B0(SBc, k2) ST_B1(SBc, k2) }
    __builtin_amdgcn_sched_barrier(0);
    MF(0, aY, bY)

    buf ^= 1;
  }
  #undef RD_A
  #undef RD_B
  #undef MF

  int row0 = m0 + wr * 128 + (hi << 2);
  int cb4 = n0 + wc * 64 + (L << 2);
  if constexpr (MODE == 0) {
    f32x4 bias; ushort* dst; bool act;
    if (cb4 < 1024)      { bias = *(const f32x4*)(b0 + cb4);          dst = oQ + cb4;          act = true;  }
    else if (cb4 < 2048) { bias = *(const f32x4*)(b1 + (cb4 - 1024)); dst = oK + (cb4 - 1024); act = true;  }
    else                 { bias = *(const f32x4*)(b2 + (cb4 - 2048)); dst = oV + (cb4 - 2048); act = false; }
    #pragma unroll
    for (int m = 0; m < 8; ++m)
      #pragma unroll
      for (int j = 0; j < 4; ++j) {
        int r = row0 + m * 16 + j;
        s16x4 w;
        #pragma unroll
        for (int n = 0; n < 4; ++n) {
          float v = acc[m][n][j] + bias[n];
          if (act) v = (v > 0.f) ? (v + 1.f) : __expf(v);   // elu(v)+1
          w[n] = (short)f2bf(v);
        }
        *(s16x4*)(dst + (size_t)r * 1024) = w;
      }
  } else {
    f32x4 bias = *(const f32x4*)(b0 + cb4);
    #pragma unroll
    for (int m = 0; m < 8; ++m)
      #pragma unroll
      for (int j = 0; j < 4; ++j) {
        int r = row0 + m * 16 + j;
        f32x4 w;
        #pragma unroll
        for (int n = 0; n < 4; ++n) w[n] = acc[m][n][j] + bias[n];
        *(f32x4*)(oF + (size_t)r * 1024 + cb4) = w;
      }
  }
}

// ---------------- stage 2: kv partials, NO atomics, no spill ---------------
__global__ __launch_bounds__(256, 2) void k_kv(
    const ushort* __restrict__ kbuf, const ushort* __restrict__ vbuf,
    float* __restrict__ kvp, float* __restrict__ skp)
{
  __shared__ ushort tile[2][8192];          // [buf][ K 8KB | V 8KB ]
  __shared__ float red[64 * 68];            // pad 64->68 floats per row
  __shared__ float skred[4][64];

  int bh = blockIdx.x >> 3, chunk = blockIdx.x & 7;
  int b = bh >> 4, h = bh & 15;
  int tid = threadIdx.x, wid = tid >> 6, lane = tid & 63;
  int d0 = (lane >> 3) << 3, e0 = (lane & 7) << 3;

  size_t gbase = ((size_t)b * 4096 + chunk * 512 + wid * 16 + (lane >> 3)) * 1024
               + h * 64 + (lane & 7) * 8;

  float acc[8][8] = {};
  float sk[8] = {};

  #define STAGE_KV(bp, c)                                                     \
  { char* base_ = (char*)&tile[bp][0] + (wid << 11);                          \
    size_t g_ = gbase + (size_t)(c) * 65536;                                  \
    load_lds16(kbuf + g_,        base_);                                      \
    load_lds16(kbuf + g_ + 8192, base_ + 1024);                               \
    load_lds16(vbuf + g_,        base_ + 8192);                               \
    load_lds16(vbuf + g_ + 8192, base_ + 9216); }

  STAGE_KV(0, 0)

  for (int c = 0; c < 8; ++c) {
    if (c + 1 < 8) {
      STAGE_KV((c + 1) & 1, c + 1)
      asm volatile("s_waitcnt vmcnt(4)" ::: "memory");   // tile c's 4 landed
    } else {
      asm volatile("s_waitcnt vmcnt(0)" ::: "memory");
    }
    __builtin_amdgcn_s_barrier();
    const ushort* Ks = &tile[c & 1][0];
    const ushort* Vs = &tile[c & 1][4096];
    #pragma unroll
    for (int t = 0; t < 16; ++t) {
      int nn = (wid << 4) + t;
      s16x8 k8 = *(const s16x8*)(Ks + nn * 64 + d0);
      s16x8 v8 = *(const s16x8*)(Vs + nn * 64 + e0);
      float kf[8], vf[8];
      #pragma unroll
      for (int i = 0; i < 8; ++i) { kf[i] = bf2f((ushort)k8[i]); vf[i] = bf2f((ushort)v8[i]); }
      #pragma unroll
      for (int i = 0; i < 8; ++i) {
        sk[i] += kf[i];
        #pragma unroll
        for (int j = 0; j < 8; ++j) acc[i][j] += kf[i] * vf[j];
      }
    }
    __builtin_amdgcn_sched_barrier(0);
    __builtin_amdgcn_s_barrier();
  }
  #undef STAGE_KV

  for (int w = 0; w < 4; ++w) {
    if (wid == w) {
      #pragma unroll
      for (int i = 0; i < 8; ++i)
        #pragma unroll
        for (int j4 = 0; j4 < 2; ++j4) {
          f32x4 v4;
          v4[0] = acc[i][j4 * 4 + 0]; v4[1] = acc[i][j4 * 4 + 1];
          v4[2] = acc[i][j4 * 4 + 2]; v4[3] = acc[i][j4 * 4 + 3];
          float* p = &red[(d0 + i) * 68 + e0 + j4 * 4];
          if (w == 0) *(f32x4*)p = v4;
          else        { f32x4 o = *(const f32x4*)p; *(f32x4*)p = o + v4; }
        }
    }
    __syncthreads();
  }

  size_t kvbase = ((size_t)chunk * 64 + bh) * 4096;
  #pragma unroll
  for (int i = 0; i < 16; ++i) {
    int el = tid + i * 256;
    kvp[kvbase + el] = red[(el >> 6) * 68 + (el & 63)];
  }
  if ((lane & 7) == 0) {
    #pragma unroll
    for (int i = 0; i < 8; ++i) skred[wid][d0 + i] = sk[i];
  }
  __syncthreads();
  if (tid < 64) {
    float s = 0.f;
    #pragma unroll
    for (int w = 0; w < 4; ++w) s += skred[w][tid];
    skp[(((size_t)chunk * 64 + bh) << 6) + tid] = s;
  }
}

// ---------------- stage 3 (MFMA): y = (q @ kv) / (q . sumk) ----------------
__global__ __launch_bounds__(512, 2) void k_num(
    const ushort* __restrict__ qbuf, const float* __restrict__ kvp,
    const float* __restrict__ skp, ushort* __restrict__ ybuf)
{
  __shared__ float kvf[4096];               // 16KB
  __shared__ ushort kvtb[4096];             // 8KB  [e][d] bf16, swizzled
  __shared__ ushort skb[64];

  int bh = blockIdx.x >> 3, chunk = blockIdx.x & 7;
  int b = bh >> 4, h = bh & 15;
  int tid = threadIdx.x, wid = tid >> 6, lane = tid & 63;
  int hi = lane >> 4, L = lane & 15;

  #pragma unroll
  for (int i = 0; i < 2; ++i) {
    int i4 = tid + i * 512;
    f32x4 s = {0.f, 0.f, 0.f, 0.f};
    #pragma unroll
    for (int sl = 0; sl < 8; ++sl)
      s += *(const f32x4*)&kvp[(((size_t)sl * 64 + bh) << 12) + ((size_t)i4 << 2)];
    *(f32x4*)&kvf[i4 << 2] = s;
  }
  if (tid < 64) {
    float s = 0.f;
    #pragma unroll
    for (int sl = 0; sl < 8; ++sl) s += skp[(((size_t)sl * 64 + bh) << 6) + tid];
    skb[tid] = f2bf(s);
  }
  __syncthreads();
  {
    int e = tid >> 3, dg = tid & 7;
    s16x8 o;
    #pragma unroll
    for (int j = 0; j < 8; ++j) o[j] = (short)f2bf(kvf[(dg * 8 + j) * 64 + e]);
    *(s16x8*)((char*)kvtb + e * 128 + ((dg ^ (e & 7)) << 4)) = o;
  }
  __syncthreads();

  size_t r0 = (size_t)b * 4096 + chunk * 512 + wid * 64;
  const ushort* qb = qbuf + (r0 + L) * 1024 + h * 64 + hi * 8;

  f32x4 acc[4][4] = {};
  f32x4 accd[4] = {};
  #pragma unroll
  for (int kk = 0; kk < 2; ++kk) {
    bf16x8 bfr[4], bfd;
    bfd = *(const bf16x8*)((const char*)skb + kk * 64 + hi * 16);  // broadcast
    #pragma unroll
    for (int n = 0; n < 4; ++n) {
      int e = L * 4 + n;
      bfr[n] = *(const bf16x8*)((char*)kvtb + e * 128 + ((((kk << 2) | hi) ^ (e & 7)) << 4));
    }
    #pragma unroll
    for (int m = 0; m < 4; ++m) {
      bf16x8 af = *(const bf16x8*)(qb + (size_t)m * 16 * 1024 + kk * 32);
      #pragma unroll
      for (int n = 0; n < 4; ++n)
        acc[m][n] = __builtin_amdgcn_mfma_f32_16x16x32_bf16(af, bfr[n], acc[m][n], 0, 0, 0);
      accd[m] = __builtin_amdgcn_mfma_f32_16x16x32_bf16(af, bfd, accd[m], 0, 0, 0);
    }
  }

  #pragma unroll
  for (int m = 0; m < 4; ++m)
    #pragma unroll
    for (int j = 0; j < 4; ++j) {
      float inv = 1.0f / accd[m][j];
      s16x4 w;
      #pragma unroll
      for (int n = 0; n < 4; ++n) w[n] = (short)f2bf(acc[m][n][j] * inv);
      *(s16x4*)(ybuf + (r0 + m * 16 + hi * 4 + j) * 1024 + h * 64 + L * 4) = w;
    }
}

extern "C" void kernel_launch(void* const* d_in, const int* in_sizes, int n_in,
                              void* d_out, int out_size, void* d_ws, size_t ws_size,
                              hipStream_t stream)
{
  const float* x  = (const float*)d_in[0];
  const float* Wq = (const float*)d_in[1];
  const float* bq = (const float*)d_in[2];
  const float* Wk = (const float*)d_in[3];
  const float* bk = (const float*)d_in[4];
  const float* Wv = (const float*)d_in[5];
  const float* bv = (const float*)d_in[6];
  const float* Wp = (const float*)d_in[7];
  const float* bp = (const float*)d_in[8];

  char* ws = (char*)d_ws;
  ushort* xb    = (ushort*)(ws + 0);          // 33,554,432 B  x in bf16 (dead after QKV)
  ushort* qkvT  = (ushort*)(ws + 33554432);   //  6,291,456 B  [Wq|Wk|Wv]^T bf16
  ushort* wpT   = (ushort*)(ws + 39845888);   //  2,097,152 B  Wp^T bf16
  ushort* ybuf  = (ushort*)(ws + 41943040);   // 33,554,432 B  k (then aliased as y)
  // kv partial slabs overlay the DEAD xb region (k_kv runs after QKV GEMM):
  float*  kvp   = (float*)(ws + 0);           //  8,388,608 B  kvp[8][64][4096]
  float*  skp   = (float*)(ws + 8388608);     //    131,072 B  skp[8][64][64]

  // v and q live in d_out (67,108,864 B of scratch, dead before final GEMM)
  ushort* vbuf = (ushort*)d_out;
  ushort* qbuf = (ushort*)d_out + 16777216;
  ushort* kbuf = ybuf;

  k_prep<<<12288, 256, 0, stream>>>(x, xb, Wq, Wk, Wv, Wp, qkvT, wpT);
  k_gemm<0><<<768, 512, 0, stream>>>(xb, qkvT, bq, bk, bv, qbuf, kbuf, vbuf, nullptr, 3072);
  k_kv<<<512, 256, 0, stream>>>(kbuf, vbuf, kvp, skp);
  k_num<<<512, 512, 0, stream>>>(qbuf, kvp, skp, ybuf);
  k_gemm<1><<<256, 512, 0, stream>>>(ybuf, wpT, bp, nullptr, nullptr,
                                     nullptr, nullptr, nullptr, (float*)d_out, 1024);
}